// Round 4
// baseline (112.655 us; speedup 1.0000x reference)
//
#include <hip/hip_runtime.h>
#include <hip/hip_bf16.h>

#define NN 4096
#define DD 512
#define NKT 16            // DD / 32 K-tiles

// ---- fused4 geometry: 256-row x 128-col tiles, 8 waves (4M x 2N), BK=32 ----
#define BMR 256
#define BNC 128
#define NJOBS 1056        // 512 xy + 272 xx + 272 yy
#define AUS 8192          // A ushorts per buffer (256*32)
#define BUS 4096          // B ushorts per buffer (128*32)
#define BUFU4 12288       // ushorts per buffer (24 KB)

// ---- fallback geometry (round-1) ----
#define BM 128
#define BK 32
#define LDP 40
#define TILES 32
#define TRI (TILES*(TILES+1)/2)

typedef __attribute__((ext_vector_type(8))) short short8v;
typedef __attribute__((ext_vector_type(4))) short short4v;
typedef __attribute__((ext_vector_type(4))) float f32x4;

static __device__ __forceinline__ short f2bf(float f) {
    union { float f; unsigned u; } a; a.f = f;
    unsigned r = a.u + 0x7FFFu + ((a.u >> 16) & 1u);
    return (short)(r >> 16);
}

static __device__ __forceinline__ void stage16(const void* g, void* l) {
    __builtin_amdgcn_global_load_lds(
        (const __attribute__((address_space(1))) unsigned int*)g,
        (__attribute__((address_space(3))) unsigned int*)l, 16, 0, 0);
}

// ---------- prep: fp32 -> bf16 ws + row norms ----------
__global__ void prep_kernel(const float* __restrict__ x, const float* __restrict__ y,
                            ushort* __restrict__ bx, ushort* __restrict__ by,
                            float* __restrict__ nx, float* __restrict__ ny) {
    int wid  = (blockIdx.x * blockDim.x + threadIdx.x) >> 6;   // 0..8191
    int lane = threadIdx.x & 63;
    bool isx = wid < NN;
    const float* src = isx ? x : y;
    ushort* dst = isx ? bx : by;
    int row = wid & (NN - 1);
    const float4* p = (const float4*)(src + (size_t)row * DD);
    float s = 0.f;
    #pragma unroll
    for (int i = 0; i < 2; ++i) {
        float4 v = p[lane + 64 * i];
        s += v.x * v.x + v.y * v.y + v.z * v.z + v.w * v.w;
        short4v h = { f2bf(v.x), f2bf(v.y), f2bf(v.z), f2bf(v.w) };
        *(short4v*)(dst + (size_t)row * DD + 4 * (lane + 64 * i)) = h;
    }
    #pragma unroll
    for (int off = 32; off > 0; off >>= 1) s += __shfl_down(s, off);
    if (lane == 0) (isx ? nx : ny)[row] = s;
}

// job -> (pass, ti(256-row tile), tj(128-col tile))
// jobs [0,512): xy full grid 16x32.
// jobs [512,784): xx upper; [784,1056): yy upper. Row-band ti has tiles
// tj in [2*ti, 32); base offset of band i is i*(33-i).
static __device__ __forceinline__ void decode_job(int j, int& p, int& ti, int& tj) {
    if (j < 512) { p = 2; ti = j >> 5; tj = j & 31; return; }
    int u = j - 512;
    p = 0;
    if (u >= 272) { p = 1; u -= 272; }
    int i = 0;
    #pragma unroll 1
    while (i < 15 && u >= (i + 1) * (33 - (i + 1))) ++i;
    ti = i;
    tj = 2 * i + (u - i * (33 - i));
}

// ---------- fused4: work-stealing, double-buffered, 1 barrier per K-tile ----------
__global__ void __launch_bounds__(512, 4)
fused4_kernel(const ushort* __restrict__ bx, const ushort* __restrict__ by,
              const float* __restrict__ nx, const float* __restrict__ ny,
              float* __restrict__ out, int* __restrict__ cnt) {
    __shared__ __align__(16) ushort lds[2 * BUFU4];   // 48 KiB
    __shared__ float wsum[8];
    __shared__ int jobS;

    const int t    = threadIdx.x;
    const int lane = t & 63;
    const int wv   = t >> 6;          // 0..7
    const int wm   = wv >> 1;         // 0..3 (64-row band of A)
    const int wn   = wv & 1;          // 0..1 (64-col band of B)
    const int fr   = lane & 15;
    // staging lane geometry (same verified swizzle as round 3: conflicts == 0)
    const int srow = lane >> 2;                              // row within 16-row seg
    const int scol = ((lane & 3) ^ ((lane >> 3) & 3)) * 8;   // inverse-swizzled src col
    const int cbs  = (((lane >> 4) ^ ((lane >> 1) & 3))) * 8;// swizzled read col

    for (;;) {
        __syncthreads();
        if (t == 0) jobS = atomicAdd(cnt, 1);
        __syncthreads();
        const int job = jobS;
        if (job >= NJOBS) break;

        int p, ti, tj;
        decode_job(job, p, ti, tj);
        const ushort* PB  = (p == 1) ? by : bx;
        const ushort* QB  = (p == 0) ? bx : by;
        const float*  NAp = (p == 1) ? ny : nx;
        const float*  NBp = (p == 0) ? nx : ny;
        const ushort* Ag = PB + (size_t)ti * BMR * DD;
        const ushort* Bg = QB + (size_t)tj * BNC * DD;

        f32x4 acc[4][4];
        #pragma unroll
        for (int m = 0; m < 4; ++m)
            #pragma unroll
            for (int n = 0; n < 4; ++n)
                acc[m][n] = (f32x4){0.f, 0.f, 0.f, 0.f};

        // --- prologue: stage K-tile 0 into buf 0 (3 segs/wave over 24 segs) ---
        {
            ushort* D = lds;
            #pragma unroll
            for (int i = 0; i < 3; ++i) {
                int s = wv * 3 + i;
                if (s < 16) stage16(Ag + (size_t)(s * 16 + srow) * DD + scol, D + s * 512);
                else        stage16(Bg + (size_t)((s - 16) * 16 + srow) * DD + scol,
                                    D + AUS + (s - 16) * 512);
            }
        }
        asm volatile("s_waitcnt vmcnt(0)" ::: "memory");
        __builtin_amdgcn_s_barrier();

        int c = 0;
        for (int kt = 0; kt < NKT; ++kt) {
            ushort* LA = lds + c * BUFU4;
            ushort* LB = LA + AUS;
            if (kt + 1 < NKT) {
                ushort* D = lds + (c ^ 1) * BUFU4;
                int ko = (kt + 1) * 32;
                #pragma unroll
                for (int i = 0; i < 3; ++i) {
                    int s = wv * 3 + i;
                    if (s < 16) stage16(Ag + (size_t)(s * 16 + srow) * DD + ko + scol, D + s * 512);
                    else        stage16(Bg + (size_t)((s - 16) * 16 + srow) * DD + ko + scol,
                                        D + AUS + (s - 16) * 512);
                }
            }
            short8v af[4], bfr[4];
            #pragma unroll
            for (int m = 0; m < 4; ++m)
                af[m] = *(const short8v*)(&LA[(wm * 64 + m * 16 + fr) * 32 + cbs]);
            #pragma unroll
            for (int n = 0; n < 4; ++n)
                bfr[n] = *(const short8v*)(&LB[(wn * 64 + n * 16 + fr) * 32 + cbs]);
            asm volatile("s_waitcnt lgkmcnt(0)" ::: "memory");
            __builtin_amdgcn_s_setprio(1);
            #pragma unroll
            for (int m = 0; m < 4; ++m)
                #pragma unroll
                for (int n = 0; n < 4; ++n)
                    acc[m][n] = __builtin_amdgcn_mfma_f32_16x16x32_bf16(af[m], bfr[n], acc[m][n], 0, 0, 0);
            __builtin_amdgcn_s_setprio(0);
            asm volatile("s_waitcnt vmcnt(0)" ::: "memory");  // own stage-writes landed
            __builtin_amdgcn_s_barrier();                     // global: reads of c done, c^1 full
            c ^= 1;
        }

        // --- epilogue ---
        float nbv[4];
        #pragma unroll
        for (int n = 0; n < 4; ++n)
            nbv[n] = NBp[tj * BNC + wn * 64 + n * 16 + fr];
        const int rbase = ((lane >> 4) << 2);

        float local = 0.f;
        #pragma unroll
        for (int m = 0; m < 4; ++m) {
            float4 na4 = *(const float4*)(&NAp[ti * BMR + wm * 64 + m * 16 + rbase]);
            float nav[4] = { na4.x, na4.y, na4.z, na4.w };
            #pragma unroll
            for (int n = 0; n < 4; ++n) {
                #pragma unroll
                for (int rr = 0; rr < 4; ++rr) {
                    int gr = ti * BMR + wm * 64 + m * 16 + rbase + rr;
                    int gc = tj * BNC + wn * 64 + n * 16 + fr;
                    float g  = acc[m][n][rr];
                    float d2 = fmaxf(nav[rr] + nbv[n] - 2.f * g, 0.f);
                    float e  = __expf(-d2);
                    if (p == 2) {
                        float diff = g - ((gr == gc) ? 1.f : 0.f);
                        local += diff * diff - 2.f * e;
                    } else {
                        float wsel = (gc > gr) ? 2.f : ((gc == gr) ? 1.f : 0.f);
                        local += wsel * e;
                    }
                }
            }
        }
        #pragma unroll
        for (int off = 32; off > 0; off >>= 1) local += __shfl_down(local, off);
        if (lane == 0) wsum[wv] = local;
        __syncthreads();
        if (t == 0) {
            float s = 0.f;
            #pragma unroll
            for (int i = 0; i < 8; ++i) s += wsum[i];
            atomicAdd(out, s * (1.f / ((float)NN * (float)NN)));
        }
    }
}

// ---------- fallback path (round-1, used only if ws too small) ----------
static __device__ __forceinline__ void decode_tile(int bid, int& p, int& ti, int& tj, float& w) {
    w = 1.f;
    if (bid < TILES * TILES) {
        p = 2; ti = bid >> 5; tj = bid & (TILES - 1);
    } else {
        int u = bid - TILES * TILES;
        p = 0;
        if (u >= TRI) { p = 1; u -= TRI; }
        int a = 0;
        while (u >= TILES - a) { u -= TILES - a; ++a; }
        ti = a; tj = a + u;
        if (ti != tj) w = 2.f;
    }
}

__global__ void norms_kernel(const float* __restrict__ x, const float* __restrict__ y,
                             float* __restrict__ nx, float* __restrict__ ny) {
    int wid  = (blockIdx.x * blockDim.x + threadIdx.x) >> 6;
    int lane = threadIdx.x & 63;
    const float* src = (wid < NN) ? x : y;
    int row = wid & (NN - 1);
    const float4* p = (const float4*)(src + (size_t)row * DD);
    float s = 0.f;
    #pragma unroll
    for (int i = 0; i < 2; ++i) {
        float4 v = p[lane + 64 * i];
        s += v.x * v.x + v.y * v.y + v.z * v.z + v.w * v.w;
    }
    #pragma unroll
    for (int off = 32; off > 0; off >>= 1) s += __shfl_down(s, off);
    if (lane == 0) ((wid < NN) ? nx : ny)[row] = s;
}

__global__ void __launch_bounds__(256)
fused_kernel(const float* __restrict__ x, const float* __restrict__ y,
             const float* __restrict__ nx, const float* __restrict__ ny,
             float* __restrict__ out) {
    __shared__ __align__(16) short As[BM * LDP];
    __shared__ __align__(16) short Bs[BM * LDP];
    __shared__ float wsum[4];

    int p, ti, tj; float w;
    decode_tile(blockIdx.x, p, ti, tj, w);
    const float* P  = (p == 1) ? y  : x;
    const float* Q  = (p == 0) ? x  : y;
    const float* NA = (p == 1) ? ny : nx;
    const float* NB = (p == 0) ? nx : ny;

    const int t    = threadIdx.x;
    const int lane = t & 63;
    const int wvid = t >> 6;
    const int wm = wvid >> 1, wn = wvid & 1;

    f32x4 acc[4][4];
    #pragma unroll
    for (int m = 0; m < 4; ++m)
        #pragma unroll
        for (int n = 0; n < 4; ++n)
            acc[m][n] = (f32x4){0.f, 0.f, 0.f, 0.f};

    const int srow = t >> 3;
    const int scol = (t & 7) * 4;
    const size_t baseA = (size_t)(ti * BM) * DD;
    const size_t baseB = (size_t)(tj * BM) * DD;

    for (int kt = 0; kt < DD; kt += BK) {
        #pragma unroll
        for (int s = 0; s < 4; ++s) {
            int r = s * 32 + srow;
            float4 va = *(const float4*)(P + baseA + (size_t)r * DD + kt + scol);
            float4 vb = *(const float4*)(Q + baseB + (size_t)r * DD + kt + scol);
            short4v ha = { f2bf(va.x), f2bf(va.y), f2bf(va.z), f2bf(va.w) };
            short4v hb = { f2bf(vb.x), f2bf(vb.y), f2bf(vb.z), f2bf(vb.w) };
            *(short4v*)(&As[r * LDP + scol]) = ha;
            *(short4v*)(&Bs[r * LDP + scol]) = hb;
        }
        __syncthreads();

        short8v af[4], bfr[4];
        const int kc = (lane >> 4) * 8;
        #pragma unroll
        for (int m = 0; m < 4; ++m)
            af[m] = *(const short8v*)(&As[(wm * 64 + m * 16 + (lane & 15)) * LDP + kc]);
        #pragma unroll
        for (int n = 0; n < 4; ++n)
            bfr[n] = *(const short8v*)(&Bs[(wn * 64 + n * 16 + (lane & 15)) * LDP + kc]);
        #pragma unroll
        for (int m = 0; m < 4; ++m)
            #pragma unroll
            for (int n = 0; n < 4; ++n)
                acc[m][n] = __builtin_amdgcn_mfma_f32_16x16x32_bf16(af[m], bfr[n], acc[m][n], 0, 0, 0);
        __syncthreads();
    }

    float local = 0.f;
    #pragma unroll
    for (int m = 0; m < 4; ++m) {
        #pragma unroll
        for (int n = 0; n < 4; ++n) {
            #pragma unroll
            for (int r = 0; r < 4; ++r) {
                int row = wm * 64 + m * 16 + ((lane >> 4) << 2) + r;
                int col = wn * 64 + n * 16 + (lane & 15);
                int gr = ti * BM + row, gc = tj * BM + col;
                float g  = acc[m][n][r];
                float d2 = fmaxf(NA[gr] + NB[gc] - 2.f * g, 0.f);
                float e  = __expf(-d2);
                if (p == 2) {
                    float diff = g - ((gr == gc) ? 1.f : 0.f);
                    local += diff * diff - 2.f * e;
                } else {
                    local += w * e;
                }
            }
        }
    }
    #pragma unroll
    for (int off = 32; off > 0; off >>= 1) local += __shfl_down(local, off);
    if (lane == 0) wsum[wvid] = local;
    __syncthreads();
    if (t == 0) {
        float s = (wsum[0] + wsum[1]) + (wsum[2] + wsum[3]);
        atomicAdd(out, s * (1.f / ((float)NN * (float)NN)));
    }
}

extern "C" void kernel_launch(void* const* d_in, const int* in_sizes, int n_in,
                              void* d_out, int out_size, void* d_ws, size_t ws_size,
                              hipStream_t stream) {
    const float* x = (const float*)d_in[0];
    const float* y = (const float*)d_in[1];
    float* out = (float*)d_out;

    hipMemsetAsync(d_out, 0, sizeof(float), stream);

    const size_t need = (size_t)2 * NN * DD * sizeof(ushort)
                      + (size_t)2 * NN * sizeof(float) + 16;
    if (ws_size >= need) {
        ushort* bx = (ushort*)d_ws;
        ushort* by = bx + (size_t)NN * DD;
        float*  nx = (float*)(by + (size_t)NN * DD);
        float*  ny = nx + NN;
        int*    cnt = (int*)(ny + NN);
        hipMemsetAsync(cnt, 0, sizeof(int), stream);
        prep_kernel<<<dim3(2048), dim3(256), 0, stream>>>(x, y, bx, by, nx, ny);
        fused4_kernel<<<dim3(512), dim3(512), 0, stream>>>(bx, by, nx, ny, out, cnt);
    } else {
        float* nx = (float*)d_ws;
        float* ny = nx + NN;
        norms_kernel<<<dim3(2048), dim3(256), 0, stream>>>(x, y, nx, ny);
        fused_kernel<<<dim3(TILES * TILES + 2 * TRI), dim3(256), 0, stream>>>(x, y, nx, ny, out);
    }
}

// Round 5
// 85.916 us; speedup vs baseline: 1.3112x; 1.3112x over previous
//
#include <hip/hip_runtime.h>
#include <hip/hip_bf16.h>

#define NN 4096
#define DD 512
#define NKT 16            // DD/32 K-tiles

// ---- fused5 geometry: 128x128 tiles, 4 waves, BK=32, double-buffered ----
#define BM 128
#define BK 32
#define BUFU5 8192        // ushorts per buffer: A 4096 + B 4096 (16 KB)
#define TILES 32
#define TRI (TILES*(TILES+1)/2)     // 528
#define NBLK (TILES*TILES + 2*TRI)  // 2080

#define LDP 40            // fallback only

typedef __attribute__((ext_vector_type(8))) short short8v;
typedef __attribute__((ext_vector_type(4))) short short4v;
typedef __attribute__((ext_vector_type(4))) float f32x4;

static __device__ __forceinline__ short f2bf(float f) {
    union { float f; unsigned u; } a; a.f = f;
    unsigned r = a.u + 0x7FFFu + ((a.u >> 16) & 1u);
    return (short)(r >> 16);
}

static __device__ __forceinline__ void stage16(const void* g, void* l) {
    __builtin_amdgcn_global_load_lds(
        (const __attribute__((address_space(1))) unsigned int*)g,
        (__attribute__((address_space(3))) unsigned int*)l, 16, 0, 0);
}

static __device__ __forceinline__ void decode_tile(int bid, int& p, int& ti, int& tj, float& w) {
    w = 1.f;
    if (bid < TILES * TILES) {
        p = 2; ti = bid >> 5; tj = bid & (TILES - 1);
    } else {
        int u = bid - TILES * TILES;
        p = 0;
        if (u >= TRI) { p = 1; u -= TRI; }
        int a = 0;
        while (u >= TILES - a) { u -= TILES - a; ++a; }
        ti = a; tj = a + u;
        if (ti != tj) w = 2.f;
    }
}

// ---------- prep: fp32 -> bf16 ws + row norms ----------
__global__ void prep_kernel(const float* __restrict__ x, const float* __restrict__ y,
                            ushort* __restrict__ bx, ushort* __restrict__ by,
                            float* __restrict__ nx, float* __restrict__ ny) {
    int wid  = (blockIdx.x * blockDim.x + threadIdx.x) >> 6;   // 0..8191
    int lane = threadIdx.x & 63;
    bool isx = wid < NN;
    const float* src = isx ? x : y;
    ushort* dst = isx ? bx : by;
    int row = wid & (NN - 1);
    const float4* p = (const float4*)(src + (size_t)row * DD);
    float s = 0.f;
    #pragma unroll
    for (int i = 0; i < 2; ++i) {
        float4 v = p[lane + 64 * i];
        s += v.x * v.x + v.y * v.y + v.z * v.z + v.w * v.w;
        short4v h = { f2bf(v.x), f2bf(v.y), f2bf(v.z), f2bf(v.w) };
        *(short4v*)(dst + (size_t)row * DD + 4 * (lane + 64 * i)) = h;
    }
    #pragma unroll
    for (int off = 32; off > 0; off >>= 1) s += __shfl_down(s, off);
    if (lane == 0) (isx ? nx : ny)[row] = s;
}

// ---------- fused5: single-barrier double-buffered K-loop ----------
__global__ void __launch_bounds__(256)
fused5_kernel(const ushort* __restrict__ bx, const ushort* __restrict__ by,
              const float* __restrict__ nx, const float* __restrict__ ny,
              float* __restrict__ out) {
    __shared__ __align__(16) ushort lds[2 * BUFU5];   // 32 KiB
    __shared__ float wsum[4];

    int p, ti, tj; float w;
    decode_tile(blockIdx.x, p, ti, tj, w);

    const ushort* PB = (p == 1) ? by : bx;
    const ushort* QB = (p == 0) ? bx : by;
    const float*  NA = (p == 1) ? ny : nx;
    const float*  NB = (p == 0) ? nx : ny;

    const int t    = threadIdx.x;
    const int lane = t & 63;
    const int wv   = t >> 6;          // 0..3
    const int wm   = wv >> 1, wn = wv & 1;
    const int fr   = lane & 15;

    // staging geometry + verified zero-conflict swizzle (rounds 3/4)
    const int srow = lane >> 2;                               // row within 16-row seg
    const int scol = ((lane & 3) ^ ((lane >> 3) & 3)) * 8;    // inverse-swizzled src col
    const int cbs  = (((lane >> 4) ^ ((lane >> 1) & 3))) * 8; // swizzled read col

    const ushort* Ag = PB + (size_t)ti * BM * DD;
    const ushort* Bg = QB + (size_t)tj * BM * DD;

    f32x4 acc[4][4];
    #pragma unroll
    for (int m = 0; m < 4; ++m)
        #pragma unroll
        for (int n = 0; n < 4; ++n)
            acc[m][n] = (f32x4){0.f, 0.f, 0.f, 0.f};

    // prologue: stage K-tile 0 into buffer 0
    #pragma unroll
    for (int i = 0; i < 2; ++i) {
        int s = wv * 2 + i;                       // 0..7
        stage16(Ag + (size_t)(s * 16 + srow) * DD + scol, lds + s * 512);
        stage16(Bg + (size_t)(s * 16 + srow) * DD + scol, lds + 4096 + s * 512);
    }
    asm volatile("s_waitcnt vmcnt(0)" ::: "memory");
    __builtin_amdgcn_s_barrier();

    int c = 0;
    #pragma unroll
    for (int kt = 0; kt < NKT; ++kt) {
        const ushort* LA = lds + c * BUFU5;
        const ushort* LB = LA + 4096;
        // 1) issue prefetch of kt+1 into the other buffer
        if (kt + 1 < NKT) {
            ushort* D = lds + (c ^ 1) * BUFU5;
            int ko = (kt + 1) * BK;
            #pragma unroll
            for (int i = 0; i < 2; ++i) {
                int s = wv * 2 + i;
                stage16(Ag + (size_t)(s * 16 + srow) * DD + ko + scol, D + s * 512);
                stage16(Bg + (size_t)(s * 16 + srow) * DD + ko + scol, D + 4096 + s * 512);
            }
        }
        // 2) ds_read current fragments (compiler inserts lgkmcnt before MFMA)
        short8v af[4], bfr[4];
        #pragma unroll
        for (int m = 0; m < 4; ++m)
            af[m] = *(const short8v*)(&LA[(wm * 64 + m * 16 + fr) * BK + cbs]);
        #pragma unroll
        for (int n = 0; n < 4; ++n)
            bfr[n] = *(const short8v*)(&LB[(wn * 64 + n * 16 + fr) * BK + cbs]);
        // 3) MFMA cluster
        __builtin_amdgcn_s_setprio(1);
        #pragma unroll
        for (int m = 0; m < 4; ++m)
            #pragma unroll
            for (int n = 0; n < 4; ++n)
                acc[m][n] = __builtin_amdgcn_mfma_f32_16x16x32_bf16(af[m], bfr[n], acc[m][n], 0, 0, 0);
        __builtin_amdgcn_s_setprio(0);
        // 4) own prefetch landed; all waves synced -> buffers swap safely
        asm volatile("s_waitcnt vmcnt(0)" ::: "memory");
        __builtin_amdgcn_s_barrier();
        c ^= 1;
    }

    // ---- epilogue ----
    float nbv[4];
    #pragma unroll
    for (int n = 0; n < 4; ++n)
        nbv[n] = NB[tj * BM + wn * 64 + n * 16 + fr];
    const int rbase = ((lane >> 4) << 2);

    float local = 0.f;
    #pragma unroll
    for (int m = 0; m < 4; ++m) {
        float4 na4 = *(const float4*)(&NA[ti * BM + wm * 64 + m * 16 + rbase]);
        float nav[4] = { na4.x, na4.y, na4.z, na4.w };
        #pragma unroll
        for (int n = 0; n < 4; ++n) {
            #pragma unroll
            for (int rr = 0; rr < 4; ++rr) {
                int gr = ti * BM + wm * 64 + m * 16 + rbase + rr;
                int gc = tj * BM + wn * 64 + n * 16 + fr;
                float g  = acc[m][n][rr];
                float d2 = fmaxf(nav[rr] + nbv[n] - 2.f * g, 0.f);
                float e  = __expf(-d2);
                if (p == 2) {
                    float diff = g - ((gr == gc) ? 1.f : 0.f);
                    local += diff * diff - 2.f * e;
                } else {
                    local += w * e;
                }
            }
        }
    }
    #pragma unroll
    for (int off = 32; off > 0; off >>= 1) local += __shfl_down(local, off);
    if (lane == 0) wsum[wv] = local;
    __syncthreads();
    if (t == 0) {
        float s = (wsum[0] + wsum[1]) + (wsum[2] + wsum[3]);
        atomicAdd(out, s * (1.f / ((float)NN * (float)NN)));
    }
}

// ---------- fallback path (round-1, used only if ws too small) ----------
__global__ void norms_kernel(const float* __restrict__ x, const float* __restrict__ y,
                             float* __restrict__ nx, float* __restrict__ ny) {
    int wid  = (blockIdx.x * blockDim.x + threadIdx.x) >> 6;
    int lane = threadIdx.x & 63;
    const float* src = (wid < NN) ? x : y;
    int row = wid & (NN - 1);
    const float4* p = (const float4*)(src + (size_t)row * DD);
    float s = 0.f;
    #pragma unroll
    for (int i = 0; i < 2; ++i) {
        float4 v = p[lane + 64 * i];
        s += v.x * v.x + v.y * v.y + v.z * v.z + v.w * v.w;
    }
    #pragma unroll
    for (int off = 32; off > 0; off >>= 1) s += __shfl_down(s, off);
    if (lane == 0) ((wid < NN) ? nx : ny)[row] = s;
}

__global__ void __launch_bounds__(256)
fused_kernel(const float* __restrict__ x, const float* __restrict__ y,
             const float* __restrict__ nx, const float* __restrict__ ny,
             float* __restrict__ out) {
    __shared__ __align__(16) short As[BM * LDP];
    __shared__ __align__(16) short Bs[BM * LDP];
    __shared__ float wsum[4];

    int p, ti, tj; float w;
    decode_tile(blockIdx.x, p, ti, tj, w);
    const float* P  = (p == 1) ? y  : x;
    const float* Q  = (p == 0) ? x  : y;
    const float* NA = (p == 1) ? ny : nx;
    const float* NB = (p == 0) ? nx : ny;

    const int t    = threadIdx.x;
    const int lane = t & 63;
    const int wvid = t >> 6;
    const int wm = wvid >> 1, wn = wvid & 1;

    f32x4 acc[4][4];
    #pragma unroll
    for (int m = 0; m < 4; ++m)
        #pragma unroll
        for (int n = 0; n < 4; ++n)
            acc[m][n] = (f32x4){0.f, 0.f, 0.f, 0.f};

    const int srow = t >> 3;
    const int scol = (t & 7) * 4;
    const size_t baseA = (size_t)(ti * BM) * DD;
    const size_t baseB = (size_t)(tj * BM) * DD;

    for (int kt = 0; kt < DD; kt += BK) {
        #pragma unroll
        for (int s = 0; s < 4; ++s) {
            int r = s * 32 + srow;
            float4 va = *(const float4*)(P + baseA + (size_t)r * DD + kt + scol);
            float4 vb = *(const float4*)(Q + baseB + (size_t)r * DD + kt + scol);
            short4v ha = { f2bf(va.x), f2bf(va.y), f2bf(va.z), f2bf(va.w) };
            short4v hb = { f2bf(vb.x), f2bf(vb.y), f2bf(vb.z), f2bf(vb.w) };
            *(short4v*)(&As[r * LDP + scol]) = ha;
            *(short4v*)(&Bs[r * LDP + scol]) = hb;
        }
        __syncthreads();

        short8v af[4], bfr[4];
        const int kc = (lane >> 4) * 8;
        #pragma unroll
        for (int m = 0; m < 4; ++m)
            af[m] = *(const short8v*)(&As[(wm * 64 + m * 16 + (lane & 15)) * LDP + kc]);
        #pragma unroll
        for (int n = 0; n < 4; ++n)
            bfr[n] = *(const short8v*)(&Bs[(wn * 64 + n * 16 + (lane & 15)) * LDP + kc]);
        #pragma unroll
        for (int m = 0; m < 4; ++m)
            #pragma unroll
            for (int n = 0; n < 4; ++n)
                acc[m][n] = __builtin_amdgcn_mfma_f32_16x16x32_bf16(af[m], bfr[n], acc[m][n], 0, 0, 0);
        __syncthreads();
    }

    float local = 0.f;
    #pragma unroll
    for (int m = 0; m < 4; ++m) {
        #pragma unroll
        for (int n = 0; n < 4; ++n) {
            #pragma unroll
            for (int r = 0; r < 4; ++r) {
                int row = wm * 64 + m * 16 + ((lane >> 4) << 2) + r;
                int col = wn * 64 + n * 16 + (lane & 15);
                int gr = ti * BM + row, gc = tj * BM + col;
                float g  = acc[m][n][r];
                float d2 = fmaxf(NA[gr] + NB[gc] - 2.f * g, 0.f);
                float e  = __expf(-d2);
                if (p == 2) {
                    float diff = g - ((gr == gc) ? 1.f : 0.f);
                    local += diff * diff - 2.f * e;
                } else {
                    local += w * e;
                }
            }
        }
    }
    #pragma unroll
    for (int off = 32; off > 0; off >>= 1) local += __shfl_down(local, off);
    if (lane == 0) wsum[wvid] = local;
    __syncthreads();
    if (t == 0) {
        float s = (wsum[0] + wsum[1]) + (wsum[2] + wsum[3]);
        atomicAdd(out, s * (1.f / ((float)NN * (float)NN)));
    }
}

extern "C" void kernel_launch(void* const* d_in, const int* in_sizes, int n_in,
                              void* d_out, int out_size, void* d_ws, size_t ws_size,
                              hipStream_t stream) {
    const float* x = (const float*)d_in[0];
    const float* y = (const float*)d_in[1];
    float* out = (float*)d_out;

    hipMemsetAsync(d_out, 0, sizeof(float), stream);

    const size_t need = (size_t)2 * NN * DD * sizeof(ushort) + (size_t)2 * NN * sizeof(float);
    if (ws_size >= need) {
        ushort* bx = (ushort*)d_ws;
        ushort* by = bx + (size_t)NN * DD;
        float*  nx = (float*)(by + (size_t)NN * DD);
        float*  ny = nx + NN;
        prep_kernel<<<dim3(2048), dim3(256), 0, stream>>>(x, y, bx, by, nx, ny);
        fused5_kernel<<<dim3(NBLK), dim3(256), 0, stream>>>(bx, by, nx, ny, out);
    } else {
        float* nx = (float*)d_ws;
        float* ny = nx + NN;
        norms_kernel<<<dim3(2048), dim3(256), 0, stream>>>(x, y, nx, ny);
        fused_kernel<<<dim3(NBLK), dim3(256), 0, stream>>>(x, y, nx, ny, out);
    }
}